// Round 4
// baseline (482.414 us; speedup 1.0000x reference)
//
#include <hip/hip_runtime.h>

#define N_NODES 307
#define T_LEN   6000
#define L1      5991
#define L2      5982
#define ED      96
#define FDIM    95712
#define NCH2    16
#define LCPC    12                  // l-chunks per channel
#define CHL     499                 // rows per l-chunk (last = 493)
#define K5CH    (NCH2 * LCPC)       // 192 K-chunks, channel-pure

// ---- workspace layout (float offsets) ----
// consts: [0..7]=s1 [8..15]=t1 [16..31]=s2 [32..47]=t2
static const size_t WS_P1 = 256;                    // conv1 stat partials: 375*16
static const size_t WS_P2 = 8192;                   // conv2 stat partials: 3740*32
static const size_t WS_CS = 131072;                 // colsum partials: 192*96
static const size_t WS_NF = 155648;                 // node_feat 307*96
static const size_t WS_SP = 188416;                 // s_proj
static const size_t WS_RP = 221184;                 // r_proj
static const size_t WS_A2 = 262144;                 // a2: 95712*320
static const size_t WS_FP = 262144 + 30627840ull;   // fc partials: 192*96*320
// total = 36,788,224 floats ~= 147.2 MB

// ================= K1: conv1 + relu, channel stats only =================
__global__ __launch_bounds__(320) void dgl_k1_conv1_stats(
    const float* __restrict__ nfeat, const float* __restrict__ w1,
    const float* __restrict__ b1, float* __restrict__ ws) {
  __shared__ float sw1[80], sb1[8];
  __shared__ float sred[5][16];
  int tid = threadIdx.x;
  if (tid < 80) sw1[tid] = w1[tid];
  if (tid < 8)  sb1[tid] = b1[tid];
  __syncthreads();
  int l0 = blockIdx.x * 16;
  int n = tid;
  bool nv = n < N_NODES;
  float xx[26];
#pragma unroll
  for (int j = 0; j < 26; ++j) {
    int t = l0 + j;
    xx[j] = (nv && t < T_LEN) ? nfeat[(size_t)t * N_NODES + n] : 0.f;
  }
  float s[8], q[8];
#pragma unroll
  for (int c = 0; c < 8; ++c) { s[c] = 0.f; q[c] = 0.f; }
#pragma unroll
  for (int dl = 0; dl < 16; ++dl) {
    int l = l0 + dl;
    if (nv && l < L1) {
#pragma unroll
      for (int c = 0; c < 8; ++c) {
        float r = sb1[c];
#pragma unroll
        for (int k = 0; k < 10; ++k) r = fmaf(xx[dl + k], sw1[c * 10 + k], r);
        float z = fmaxf(r, 0.f);
        s[c] += z; q[c] += z * z;
      }
    }
  }
  int wv = tid >> 6, ln = tid & 63;
#pragma unroll
  for (int c = 0; c < 8; ++c) {
    float vs = s[c], vq = q[c];
    for (int o = 32; o; o >>= 1) { vs += __shfl_down(vs, o, 64); vq += __shfl_down(vq, o, 64); }
    if (ln == 0) { sred[wv][c] = vs; sred[wv][8 + c] = vq; }
  }
  __syncthreads();
  if (tid < 16) {
    float t = 0.f;
    for (int w = 0; w < 5; ++w) t += sred[w][tid];
    ws[WS_P1 + (size_t)blockIdx.x * 16 + tid] = t;
  }
}

// ================= K2: finalize bn1 =================
__global__ void dgl_k2_fin1(const float* __restrict__ g1, const float* __restrict__ b1,
                            float* __restrict__ ws) {
  __shared__ double sd[16];
  int tid = threadIdx.x;
  if (tid < 16) {
    double a = 0.0;
    for (int j = 0; j < 375; ++j) a += (double)ws[WS_P1 + (size_t)j * 16 + tid];
    sd[tid] = a;
  }
  __syncthreads();
  if (tid < 8) {
    double cnt = (double)N_NODES * (double)L1;
    double m = sd[tid] / cnt;
    double v = sd[tid + 8] / cnt - m * m;
    double inv = 1.0 / sqrt(v + 1e-5);
    ws[tid]     = (float)((double)g1[tid] * inv);
    ws[8 + tid] = (float)((double)b1[tid] - (double)g1[tid] * inv * m);
  }
}

// ================= K3: fused conv1+bn1 (reg window) -> conv2 (2 passes) + relu -> a2 + stats =================
__global__ __launch_bounds__(256) void dgl_k3_conv2(
    const float* __restrict__ nfeat, const float* __restrict__ w1, const float* __restrict__ b1,
    const float* __restrict__ w2, const float* __restrict__ b2, float* __restrict__ ws) {
  __shared__ float sz[4][17][64];
  __shared__ float sw2[1280], sw1[80], sb1[8], sb2[16], ss1[8], st1[8];
  __shared__ float wpart[4][8];
  int tid = threadIdx.x;
  int lane = tid & 63, g = tid >> 6;
  int l0 = blockIdx.x * 8, n0 = blockIdx.y * 64;
  for (int i = tid; i < 1280; i += 256) sw2[i] = w2[i];
  if (tid < 80) sw1[tid] = w1[tid];
  if (tid < 8)  { sb1[tid] = b1[tid]; ss1[tid] = ws[tid]; st1[tid] = ws[8 + tid]; }
  if (tid < 16) sb2[tid] = b2[tid];
  int n = n0 + lane;
  bool nv = n < N_NODES;
  float sxr[26];
#pragma unroll
  for (int j = 0; j < 26; ++j) {
    int t = l0 + j;
    sxr[j] = (nv && t < T_LEN) ? nfeat[(size_t)t * N_NODES + n] : 0.f;
  }
  float acc[4][8];
#pragma unroll
  for (int qq = 0; qq < 4; ++qq)
#pragma unroll
    for (int dl = 0; dl < 8; ++dl) acc[qq][dl] = 0.f;
  __syncthreads();   // smalls staged
#pragma unroll
  for (int p = 0; p < 2; ++p) {
    // build z1 for channels p*4 .. p*4+3 ; group g builds channel p*4+g
    {
      int c = p * 4 + g;
#pragma unroll
      for (int lz = 0; lz < 17; ++lz) {
        float r = sb1[c];
#pragma unroll
        for (int k = 0; k < 10; ++k) r = fmaf(sxr[lz + k], sw1[c * 10 + k], r);
        sz[g][lz][lane] = fmaf(ss1[c], fmaxf(r, 0.f), st1[c]);
      }
    }
    __syncthreads();
#pragma unroll
    for (int c4 = 0; c4 < 4; ++c4) {
      int cin = p * 4 + c4;
      float zr[17];
#pragma unroll
      for (int t = 0; t < 17; ++t) zr[t] = sz[c4][t][lane];
#pragma unroll
      for (int k = 0; k < 10; ++k) {
#pragma unroll
        for (int qq = 0; qq < 4; ++qq) {
          float w = sw2[(g * 4 + qq) * 80 + cin * 10 + k];
#pragma unroll
          for (int dl = 0; dl < 8; ++dl) acc[qq][dl] = fmaf(zr[dl + k], w, acc[qq][dl]);
        }
      }
    }
    __syncthreads();
  }
  float s4[4] = {0.f, 0.f, 0.f, 0.f}, q4[4] = {0.f, 0.f, 0.f, 0.f};
#pragma unroll
  for (int qq = 0; qq < 4; ++qq) {
    int c2 = g * 4 + qq;
#pragma unroll
    for (int dl = 0; dl < 8; ++dl) {
      int l = l0 + dl;
      float v = 0.f;
      if (nv && l < L2) v = fmaxf(acc[qq][dl] + sb2[c2], 0.f);
      if (l < L2) ws[WS_A2 + ((size_t)c2 * L2 + l) * 320 + n] = v;
      s4[qq] += v; q4[qq] += v * v;
    }
  }
#pragma unroll
  for (int qq = 0; qq < 4; ++qq) {
    float vs = s4[qq], vq = q4[qq];
    for (int o = 32; o; o >>= 1) { vs += __shfl_down(vs, o, 64); vq += __shfl_down(vq, o, 64); }
    if (lane == 0) { wpart[g][qq] = vs; wpart[g][4 + qq] = vq; }
  }
  __syncthreads();
  if (tid < 32) {
    int c2 = tid & 15; bool isq = tid >= 16;
    float v = wpart[c2 >> 2][(isq ? 4 : 0) + (c2 & 3)];
    ws[WS_P2 + ((size_t)blockIdx.y * gridDim.x + blockIdx.x) * 32 + tid] = v;
  }
}

// ================= K4: finalize bn2 =================
__global__ __launch_bounds__(512) void dgl_k4_fin2(const float* __restrict__ g2,
                                                   const float* __restrict__ b2,
                                                   float* __restrict__ ws) {
  __shared__ double dd[32][17];
  int tid = threadIdx.x;
  int v = tid >> 4, p = tid & 15;
  double a = 0.0;
  for (int j = p; j < 3740; j += 16) a += (double)ws[WS_P2 + (size_t)j * 32 + v];
  dd[v][p] = a;
  __syncthreads();
  if (tid < 32) {
    double s = 0.0;
    for (int pp = 0; pp < 16; ++pp) s += dd[tid][pp];
    dd[tid][16] = s;
  }
  __syncthreads();
  if (tid < 16) {
    double cnt = (double)N_NODES * (double)L2;
    double m = dd[tid][16] / cnt;
    double var = dd[tid + 16][16] / cnt - m * m;
    double inv = 1.0 / sqrt(var + 1e-5);
    ws[16 + tid] = (float)((double)g2[tid] * inv);
    ws[32 + tid] = (float)((double)b2[tid] - (double)g2[tid] * inv * m);
  }
}

// ================= K4b: per-channel-chunk column sums of fc_w =================
__global__ __launch_bounds__(384) void dgl_k4b_colsum(const float* __restrict__ fcw,
                                                      float* __restrict__ ws) {
  __shared__ float red[4][96];
  int b = blockIdx.x;                 // 0..191
  int c = b / LCPC, lc = b % LCPC;
  int clen = (lc == LCPC - 1) ? (L2 - CHL * (LCPC - 1)) : CHL;
  size_t fb = (size_t)c * L2 + (size_t)lc * CHL;
  int tid = threadIdx.x, rg = tid / 96, e = tid % 96;
  float a = 0.f;
  for (int r = rg; r < clen; r += 4) a += fcw[(fb + r) * 96 + e];
  red[rg][e] = a;
  __syncthreads();
  if (tid < 96) {
    float t = red[0][tid] + red[1][tid] + red[2][tid] + red[3][tid];
    ws[WS_CS + (size_t)b * 96 + tid] = t;
  }
}

// ================= K5: split-K GEMM on raw a2, channel-pure chunks, reg-prefetch =================
__global__ __launch_bounds__(192) void dgl_k5_fc(const float* __restrict__ fcw,
                                                 float* __restrict__ ws) {
  __shared__ float As[16][36];
  __shared__ float Bs[16][100];
  int tid = threadIdx.x;
  int ch = blockIdx.x;                // 0..191
  int c = ch / LCPC, lc = ch % LCPC;
  int clen = (lc == LCPC - 1) ? (L2 - CHL * (LCPC - 1)) : CHL;
  size_t fb = (size_t)c * L2 + (size_t)lc * CHL;
  int n0 = blockIdx.y * 32;
  const float* a2 = ws + WS_A2;
  int tn = tid / 24, te = tid % 24;   // thread tile 4n x 4e
  float acc[4][4];
#pragma unroll
  for (int i = 0; i < 4; ++i)
#pragma unroll
    for (int j = 0; j < 4; ++j) acc[i][j] = 0.f;
  int ar = tid >> 3, ac = tid & 7;                       // A staging (tid<128)
  int br0 = tid / 24, bc0 = tid % 24;                    // B staging slot 0
  int br1 = (tid + 192) / 24, bc1 = (tid + 192) % 24;    // B staging slot 1
  const float4 z4 = make_float4(0.f, 0.f, 0.f, 0.f);
  float4 va = z4, vb0 = z4, vb1 = z4;

#define K5_LOAD(KS) do { int r0_ = (KS) * 16;                                   \
    if (tid < 128) { int r_ = r0_ + ar;                                         \
      va = (r_ < clen) ? *(const float4*)(a2 + (fb + r_) * 320 + n0 + ac * 4)   \
                       : z4; }                                                  \
    { int r_ = r0_ + br0;                                                       \
      vb0 = (r_ < clen) ? *(const float4*)(fcw + (fb + r_) * 96 + bc0 * 4)      \
                        : z4; }                                                 \
    { int r_ = r0_ + br1;                                                       \
      vb1 = (r_ < clen) ? *(const float4*)(fcw + (fb + r_) * 96 + bc1 * 4)      \
                        : z4; }                                                 \
  } while (0)

#define K5_STORE() do {                                                         \
    if (tid < 128) *(float4*)(&As[ar][ac * 4]) = va;                            \
    *(float4*)(&Bs[br0][bc0 * 4]) = vb0;                                        \
    *(float4*)(&Bs[br1][bc1 * 4]) = vb1;                                        \
  } while (0)

  K5_LOAD(0);
  K5_STORE();
  __syncthreads();
  for (int ks = 0; ks < 32; ++ks) {
    if (ks < 31) K5_LOAD(ks + 1);
#pragma unroll
    for (int kk = 0; kk < 16; ++kk) {
      float a[4], b[4];
      *(float4*)(a) = *(float4*)(&As[kk][tn * 4]);
      *(float4*)(b) = *(float4*)(&Bs[kk][te * 4]);
#pragma unroll
      for (int i = 0; i < 4; ++i)
#pragma unroll
        for (int j = 0; j < 4; ++j) acc[i][j] = fmaf(a[i], b[j], acc[i][j]);
    }
    __syncthreads();
    if (ks < 31) { K5_STORE(); __syncthreads(); }
  }
  float* fp = ws + WS_FP;
#pragma unroll
  for (int j = 0; j < 4; ++j) {
    int e = te * 4 + j;
    size_t base = ((size_t)ch * 96 + e) * 320 + n0 + tn * 4;
    float4 o = {acc[0][j], acc[1][j], acc[2][j], acc[3][j]};
    *(float4*)(fp + base) = o;
  }
}

// ================= K6: fp64 combine (s2*P + t2*colsum + fcb) + relu + bn3 =================
__global__ __launch_bounds__(320) void dgl_k6_bn3(const float* __restrict__ fcb,
                                                  const float* __restrict__ g3,
                                                  const float* __restrict__ b3,
                                                  float* __restrict__ ws) {
  int e = blockIdx.x, tid = threadIdx.x;
  __shared__ double s2d[16], csd[16];
  __shared__ double rs[5], rq[5];
  __shared__ float mb[2];
  if (tid < 16) {
    s2d[tid] = (double)ws[16 + tid];
    double a = 0.0;
#pragma unroll
    for (int lc = 0; lc < LCPC; ++lc)
      a += (double)ws[WS_CS + (size_t)(tid * LCPC + lc) * 96 + e];
    csd[tid] = a * (double)ws[32 + tid];   // t2[c] * colsum_c[e]
  }
  __syncthreads();
  const float* fp = ws + WS_FP;
  double a = 0.0;
#pragma unroll 2
  for (int c = 0; c < 16; ++c) {
    double pc = 0.0;
    for (int lc = 0; lc < LCPC; ++lc) {
      int ch = c * LCPC + lc;
      pc += (double)fp[((size_t)ch * 96 + e) * 320 + tid];
    }
    a += s2d[c] * pc;
  }
  double cst = 0.0;
#pragma unroll
  for (int c = 0; c < 16; ++c) cst += csd[c];
  float x = fmaxf((float)(a + cst) + fcb[e], 0.f);
  if (tid >= N_NODES) x = 0.f;
  double s = (double)x, q = (double)x * (double)x;
  int wv = tid >> 6, ln = tid & 63;
  for (int o = 32; o; o >>= 1) { s += __shfl_down(s, o, 64); q += __shfl_down(q, o, 64); }
  if (ln == 0) { rs[wv] = s; rq[wv] = q; }
  __syncthreads();
  if (tid == 0) {
    double S = 0.0, Q = 0.0;
    for (int w = 0; w < 5; ++w) { S += rs[w]; Q += rq[w]; }
    double m = S / (double)N_NODES;
    double var = Q / (double)N_NODES - m * m;
    mb[0] = (float)m; mb[1] = (float)(1.0 / sqrt(var + 1e-5));
  }
  __syncthreads();
  if (tid < N_NODES)
    ws[WS_NF + (size_t)tid * 96 + e] = g3[e] * (x - mb[0]) * mb[1] + b3[e];
}

// ================= K7: s_proj / r_proj =================
__global__ __launch_bounds__(192) void dgl_k7_proj(const float* __restrict__ fow,
                                                   float* __restrict__ ws) {
  __shared__ float sh[96];
  int nI = blockIdx.x, tid = threadIdx.x;
  if (tid < 96) sh[tid] = ws[WS_NF + (size_t)nI * 96 + tid];
  __syncthreads();
  int col = tid % 96, half = tid / 96;
  float a = 0.f;
#pragma unroll 8
  for (int d = 0; d < 96; ++d) a = fmaf(sh[d], fow[(size_t)(half * 96 + d) * 96 + col], a);
  ws[(half ? WS_RP : WS_SP) + (size_t)nI * 96 + col] = a;
}

// ================= K8: edge relu + logits + gumbel + hard argmax -> adj =================
__global__ __launch_bounds__(256) void dgl_k8_edge(const float* __restrict__ fob,
                                                   const float* __restrict__ fcatw,
                                                   const float* __restrict__ fcatb,
                                                   const float* __restrict__ unif,
                                                   const float* __restrict__ ws,
                                                   float* __restrict__ out) {
  __shared__ float rp[16][100], sp[16][100], bb[96], wa[96], wb[96];
  int tid = threadIdx.x;
  int i0 = blockIdx.y * 16, j0 = blockIdx.x * 16;
  for (int idx = tid; idx < 16 * 96; idx += 256) {
    int r = idx / 96, e = idx % 96;
    int ii = i0 + r, jj = j0 + r;
    rp[r][e] = (ii < N_NODES) ? ws[WS_RP + (size_t)ii * 96 + e] : 0.f;
    sp[r][e] = (jj < N_NODES) ? ws[WS_SP + (size_t)jj * 96 + e] : 0.f;
  }
  if (tid < 96) { bb[tid] = fob[tid]; wa[tid] = fcatw[2 * tid]; wb[tid] = fcatw[2 * tid + 1]; }
  __syncthreads();
  int il = tid >> 4, jl = tid & 15;
  int i = i0 + il, j = j0 + jl;
  float a0 = 0.f, a1 = 0.f;
#pragma unroll 4
  for (int e = 0; e < 96; ++e) {
    float ef = fmaxf(rp[il][e] + sp[jl][e] + bb[e], 0.f);
    a0 = fmaf(ef, wa[e], a0);
    a1 = fmaf(ef, wb[e], a1);
  }
  if (i < N_NODES && j < N_NODES) {
    size_t ue = ((size_t)i * N_NODES + j) * 2;
    float g0 = -logf(-logf(unif[ue] + 1e-20f) + 1e-20f);
    float g1 = -logf(-logf(unif[ue + 1] + 1e-20f) + 1e-20f);
    float z0 = a0 + fcatb[0] + g0;
    float z1 = a1 + fcatb[1] + g1;
    out[(size_t)i * N_NODES + j] = (i == j) ? 0.f : ((z0 >= z1) ? 1.f : 0.f);
  }
}

extern "C" void kernel_launch(void* const* d_in, const int* in_sizes, int n_in,
                              void* d_out, int out_size, void* d_ws, size_t ws_size,
                              hipStream_t stream) {
  const float* nfeat = (const float*)d_in[1];
  const float* w1    = (const float*)d_in[2];
  const float* b1    = (const float*)d_in[3];
  const float* w2    = (const float*)d_in[4];
  const float* b2    = (const float*)d_in[5];
  const float* g1    = (const float*)d_in[6];
  const float* bb1   = (const float*)d_in[7];
  const float* g2    = (const float*)d_in[8];
  const float* bb2   = (const float*)d_in[9];
  const float* g3    = (const float*)d_in[10];
  const float* bb3   = (const float*)d_in[11];
  const float* fcw   = (const float*)d_in[12];
  const float* fcb   = (const float*)d_in[13];
  const float* fow   = (const float*)d_in[14];
  const float* fob   = (const float*)d_in[15];
  const float* fcatw = (const float*)d_in[16];
  const float* fcatb = (const float*)d_in[17];
  const float* unif  = (const float*)d_in[18];
  float* ws  = (float*)d_ws;
  float* out = (float*)d_out;

  dgl_k4b_colsum<<<dim3(K5CH), dim3(384), 0, stream>>>(fcw, ws);
  dgl_k1_conv1_stats<<<dim3(375), dim3(320), 0, stream>>>(nfeat, w1, b1, ws);
  dgl_k2_fin1<<<dim3(1), dim3(64), 0, stream>>>(g1, bb1, ws);
  dgl_k3_conv2<<<dim3(748, 5), dim3(256), 0, stream>>>(nfeat, w1, b1, w2, b2, ws);
  dgl_k4_fin2<<<dim3(1), dim3(512), 0, stream>>>(g2, bb2, ws);
  dgl_k5_fc<<<dim3(K5CH, 10), dim3(192), 0, stream>>>(fcw, ws);
  dgl_k6_bn3<<<dim3(96), dim3(320), 0, stream>>>(fcb, g3, bb3, ws);
  dgl_k7_proj<<<dim3(307), dim3(192), 0, stream>>>(fow, ws);
  dgl_k8_edge<<<dim3(20, 20), dim3(256), 0, stream>>>(fob, fcatw, fcatb, unif, ws, out);
}

// Round 5
// 343.571 us; speedup vs baseline: 1.4041x; 1.4041x over previous
//
#include <hip/hip_runtime.h>

#define N_NODES 307
#define T_LEN   6000
#define L1      5991
#define L2      5982
#define ED      96
#define FDIM    95712
#define NCH2    16
#define LCPC    12                  // l-chunks per channel
#define CHL     499                 // rows per l-chunk (last = 493)
#define K5CH    (NCH2 * LCPC)       // 192 K-chunks, channel-pure

// ---- workspace layout (float offsets) ----
// consts: [0..7]=s1 [8..15]=t1 [16..31]=s2 [32..47]=t2
static const size_t WS_P1 = 256;                    // conv1 stat partials: 375*16
static const size_t WS_P2 = 8192;                   // conv2 stat partials: 3740*32
static const size_t WS_CS = 131072;                 // colsum partials: 192*96
static const size_t WS_NF = 155648;                 // node_feat 307*96
static const size_t WS_SP = 188416;                 // s_proj
static const size_t WS_RP = 221184;                 // r_proj
static const size_t WS_A2 = 262144;                 // a2: 95712*320
static const size_t WS_FP = 262144 + 30627840ull;   // fc partials: 192*96*320
// total = 36,788,224 floats ~= 147.2 MB

// ================= K1: conv1 + relu, channel stats only =================
__global__ __launch_bounds__(320) void dgl_k1_conv1_stats(
    const float* __restrict__ nfeat, const float* __restrict__ w1,
    const float* __restrict__ b1, float* __restrict__ ws) {
  __shared__ float sw1[80], sb1[8];
  __shared__ float sred[5][16];
  int tid = threadIdx.x;
  if (tid < 80) sw1[tid] = w1[tid];
  if (tid < 8)  sb1[tid] = b1[tid];
  __syncthreads();
  int l0 = blockIdx.x * 16;
  int n = tid;
  bool nv = n < N_NODES;
  float xx[26];
#pragma unroll
  for (int j = 0; j < 26; ++j) {
    int t = l0 + j;
    xx[j] = (nv && t < T_LEN) ? nfeat[(size_t)t * N_NODES + n] : 0.f;
  }
  float s[8], q[8];
#pragma unroll
  for (int c = 0; c < 8; ++c) { s[c] = 0.f; q[c] = 0.f; }
#pragma unroll
  for (int dl = 0; dl < 16; ++dl) {
    int l = l0 + dl;
    if (nv && l < L1) {
#pragma unroll
      for (int c = 0; c < 8; ++c) {
        float r = sb1[c];
#pragma unroll
        for (int k = 0; k < 10; ++k) r = fmaf(xx[dl + k], sw1[c * 10 + k], r);
        float z = fmaxf(r, 0.f);
        s[c] += z; q[c] += z * z;
      }
    }
  }
  int wv = tid >> 6, ln = tid & 63;
#pragma unroll
  for (int c = 0; c < 8; ++c) {
    float vs = s[c], vq = q[c];
    for (int o = 32; o; o >>= 1) { vs += __shfl_down(vs, o, 64); vq += __shfl_down(vq, o, 64); }
    if (ln == 0) { sred[wv][c] = vs; sred[wv][8 + c] = vq; }
  }
  __syncthreads();
  if (tid < 16) {
    float t = 0.f;
    for (int w = 0; w < 5; ++w) t += sred[w][tid];
    ws[WS_P1 + (size_t)blockIdx.x * 16 + tid] = t;
  }
}

// ================= K2: finalize bn1 =================
__global__ void dgl_k2_fin1(const float* __restrict__ g1, const float* __restrict__ b1,
                            float* __restrict__ ws) {
  __shared__ double sd[16];
  int tid = threadIdx.x;
  if (tid < 16) {
    double a = 0.0;
    for (int j = 0; j < 375; ++j) a += (double)ws[WS_P1 + (size_t)j * 16 + tid];
    sd[tid] = a;
  }
  __syncthreads();
  if (tid < 8) {
    double cnt = (double)N_NODES * (double)L1;
    double m = sd[tid] / cnt;
    double v = sd[tid + 8] / cnt - m * m;
    double inv = 1.0 / sqrt(v + 1e-5);
    ws[tid]     = (float)((double)g1[tid] * inv);
    ws[8 + tid] = (float)((double)b1[tid] - (double)g1[tid] * inv * m);
  }
}

// ================= K3: fused conv1+bn1 (LDS window) -> conv2 (2 passes) + relu -> a2 + stats =================
__global__ __launch_bounds__(256, 4) void dgl_k3_conv2(
    const float* __restrict__ nfeat, const float* __restrict__ w1, const float* __restrict__ b1,
    const float* __restrict__ w2, const float* __restrict__ b2, float* __restrict__ ws) {
  __shared__ float sx[26][64];
  __shared__ float sz[4][17][64];
  __shared__ float sw2[1280], sw1[80], sb1[8], sb2[16], ss1[8], st1[8];
  __shared__ float wpart[4][8];
  int tid = threadIdx.x;
  int lane = tid & 63, g = tid >> 6;
  int l0 = blockIdx.x * 8, n0 = blockIdx.y * 64;
  for (int i = tid; i < 1280; i += 256) sw2[i] = w2[i];
  if (tid < 80) sw1[tid] = w1[tid];
  if (tid < 8)  { sb1[tid] = b1[tid]; ss1[tid] = ws[tid]; st1[tid] = ws[8 + tid]; }
  if (tid < 16) sb2[tid] = b2[tid];
  for (int i = tid; i < 26 * 64; i += 256) {
    int j = i >> 6, l2 = i & 63;
    int t = l0 + j, nn = n0 + l2;
    sx[j][l2] = (t < T_LEN && nn < N_NODES) ? nfeat[(size_t)t * N_NODES + nn] : 0.f;
  }
  float acc[4][8];
#pragma unroll
  for (int qq = 0; qq < 4; ++qq)
#pragma unroll
    for (int dl = 0; dl < 8; ++dl) acc[qq][dl] = 0.f;
  __syncthreads();
#pragma unroll 1
  for (int p = 0; p < 2; ++p) {
    // group g builds z1 for channel p*4+g into sz[g]
    {
      int c = p * 4 + g;
#pragma unroll
      for (int lz = 0; lz < 17; ++lz) {
        float r = sb1[c];
#pragma unroll
        for (int k = 0; k < 10; ++k) r = fmaf(sx[lz + k][lane], sw1[c * 10 + k], r);
        sz[g][lz][lane] = fmaf(ss1[c], fmaxf(r, 0.f), st1[c]);
      }
    }
    __syncthreads();
#pragma unroll
    for (int c4 = 0; c4 < 4; ++c4) {
      int cin = p * 4 + c4;
      float zr[17];
#pragma unroll
      for (int t = 0; t < 17; ++t) zr[t] = sz[c4][t][lane];
#pragma unroll
      for (int k = 0; k < 10; ++k) {
#pragma unroll
        for (int qq = 0; qq < 4; ++qq) {
          float w = sw2[(g * 4 + qq) * 80 + cin * 10 + k];
#pragma unroll
          for (int dl = 0; dl < 8; ++dl) acc[qq][dl] = fmaf(zr[dl + k], w, acc[qq][dl]);
        }
      }
    }
    __syncthreads();
  }
  int n = n0 + lane;
  bool nv = n < N_NODES;
  float s4[4] = {0.f, 0.f, 0.f, 0.f}, q4[4] = {0.f, 0.f, 0.f, 0.f};
#pragma unroll
  for (int qq = 0; qq < 4; ++qq) {
    int c2 = g * 4 + qq;
#pragma unroll
    for (int dl = 0; dl < 8; ++dl) {
      int l = l0 + dl;
      float v = 0.f;
      if (nv && l < L2) v = fmaxf(acc[qq][dl] + sb2[c2], 0.f);
      if (l < L2) ws[WS_A2 + ((size_t)c2 * L2 + l) * 320 + n] = v;
      s4[qq] += v; q4[qq] += v * v;
    }
  }
#pragma unroll
  for (int qq = 0; qq < 4; ++qq) {
    float vs = s4[qq], vq = q4[qq];
    for (int o = 32; o; o >>= 1) { vs += __shfl_down(vs, o, 64); vq += __shfl_down(vq, o, 64); }
    if (lane == 0) { wpart[g][qq] = vs; wpart[g][4 + qq] = vq; }
  }
  __syncthreads();
  if (tid < 32) {
    int c2 = tid & 15; bool isq = tid >= 16;
    float v = wpart[c2 >> 2][(isq ? 4 : 0) + (c2 & 3)];
    ws[WS_P2 + ((size_t)blockIdx.y * gridDim.x + blockIdx.x) * 32 + tid] = v;
  }
}

// ================= K4: finalize bn2 =================
__global__ __launch_bounds__(512) void dgl_k4_fin2(const float* __restrict__ g2,
                                                   const float* __restrict__ b2,
                                                   float* __restrict__ ws) {
  __shared__ double dd[32][17];
  int tid = threadIdx.x;
  int v = tid >> 4, p = tid & 15;
  double a = 0.0;
  for (int j = p; j < 3740; j += 16) a += (double)ws[WS_P2 + (size_t)j * 32 + v];
  dd[v][p] = a;
  __syncthreads();
  if (tid < 32) {
    double s = 0.0;
    for (int pp = 0; pp < 16; ++pp) s += dd[tid][pp];
    dd[tid][16] = s;
  }
  __syncthreads();
  if (tid < 16) {
    double cnt = (double)N_NODES * (double)L2;
    double m = dd[tid][16] / cnt;
    double var = dd[tid + 16][16] / cnt - m * m;
    double inv = 1.0 / sqrt(var + 1e-5);
    ws[16 + tid] = (float)((double)g2[tid] * inv);
    ws[32 + tid] = (float)((double)b2[tid] - (double)g2[tid] * inv * m);
  }
}

// ================= K4b: per-channel-chunk column sums of fc_w =================
__global__ __launch_bounds__(384) void dgl_k4b_colsum(const float* __restrict__ fcw,
                                                      float* __restrict__ ws) {
  __shared__ float red[4][96];
  int b = blockIdx.x;                 // 0..191
  int c = b / LCPC, lc = b % LCPC;
  int clen = (lc == LCPC - 1) ? (L2 - CHL * (LCPC - 1)) : CHL;
  size_t fb = (size_t)c * L2 + (size_t)lc * CHL;
  int tid = threadIdx.x, rg = tid / 96, e = tid % 96;
  float a = 0.f;
  for (int r = rg; r < clen; r += 4) a += fcw[(fb + r) * 96 + e];
  red[rg][e] = a;
  __syncthreads();
  if (tid < 96) {
    float t = red[0][tid] + red[1][tid] + red[2][tid] + red[3][tid];
    ws[WS_CS + (size_t)b * 96 + tid] = t;
  }
}

// ================= K5: split-K GEMM on raw a2, channel-pure chunks, reg-prefetch =================
__global__ __launch_bounds__(192) void dgl_k5_fc(const float* __restrict__ fcw,
                                                 float* __restrict__ ws) {
  __shared__ float As[16][36];
  __shared__ float Bs[16][100];
  int tid = threadIdx.x;
  int ch = blockIdx.x;                // 0..191
  int c = ch / LCPC, lc = ch % LCPC;
  int clen = (lc == LCPC - 1) ? (L2 - CHL * (LCPC - 1)) : CHL;
  size_t fb = (size_t)c * L2 + (size_t)lc * CHL;
  int n0 = blockIdx.y * 32;
  const float* a2 = ws + WS_A2;
  int tn = tid / 24, te = tid % 24;   // thread tile 4n x 4e
  float acc[4][4];
#pragma unroll
  for (int i = 0; i < 4; ++i)
#pragma unroll
    for (int j = 0; j < 4; ++j) acc[i][j] = 0.f;
  int ar = tid >> 3, ac = tid & 7;                       // A staging (tid<128)
  int br0 = tid / 24, bc0 = tid % 24;                    // B staging slot 0
  int br1 = (tid + 192) / 24, bc1 = (tid + 192) % 24;    // B staging slot 1
  const float4 z4 = make_float4(0.f, 0.f, 0.f, 0.f);
  float4 va = z4, vb0 = z4, vb1 = z4;

#define K5_LOAD(KS) do { int r0_ = (KS) * 16;                                   \
    if (tid < 128) { int r_ = r0_ + ar;                                         \
      va = (r_ < clen) ? *(const float4*)(a2 + (fb + r_) * 320 + n0 + ac * 4)   \
                       : z4; }                                                  \
    { int r_ = r0_ + br0;                                                       \
      vb0 = (r_ < clen) ? *(const float4*)(fcw + (fb + r_) * 96 + bc0 * 4)      \
                        : z4; }                                                 \
    { int r_ = r0_ + br1;                                                       \
      vb1 = (r_ < clen) ? *(const float4*)(fcw + (fb + r_) * 96 + bc1 * 4)      \
                        : z4; }                                                 \
  } while (0)

#define K5_STORE() do {                                                         \
    if (tid < 128) *(float4*)(&As[ar][ac * 4]) = va;                            \
    *(float4*)(&Bs[br0][bc0 * 4]) = vb0;                                        \
    *(float4*)(&Bs[br1][bc1 * 4]) = vb1;                                        \
  } while (0)

  K5_LOAD(0);
  K5_STORE();
  __syncthreads();
  for (int ks = 0; ks < 32; ++ks) {
    if (ks < 31) K5_LOAD(ks + 1);
#pragma unroll
    for (int kk = 0; kk < 16; ++kk) {
      float a[4], b[4];
      *(float4*)(a) = *(float4*)(&As[kk][tn * 4]);
      *(float4*)(b) = *(float4*)(&Bs[kk][te * 4]);
#pragma unroll
      for (int i = 0; i < 4; ++i)
#pragma unroll
        for (int j = 0; j < 4; ++j) acc[i][j] = fmaf(a[i], b[j], acc[i][j]);
    }
    __syncthreads();
    if (ks < 31) { K5_STORE(); __syncthreads(); }
  }
  float* fp = ws + WS_FP;
#pragma unroll
  for (int j = 0; j < 4; ++j) {
    int e = te * 4 + j;
    size_t base = ((size_t)ch * 96 + e) * 320 + n0 + tn * 4;
    float4 o = {acc[0][j], acc[1][j], acc[2][j], acc[3][j]};
    *(float4*)(fp + base) = o;
  }
}

// ================= K6: fp64 combine (s2*P + t2*colsum + fcb) + relu + bn3 =================
__global__ __launch_bounds__(320) void dgl_k6_bn3(const float* __restrict__ fcb,
                                                  const float* __restrict__ g3,
                                                  const float* __restrict__ b3,
                                                  float* __restrict__ ws) {
  int e = blockIdx.x, tid = threadIdx.x;
  __shared__ double s2d[16], csd[16];
  __shared__ double rs[5], rq[5];
  __shared__ float mb[2];
  if (tid < 16) {
    s2d[tid] = (double)ws[16 + tid];
    double a = 0.0;
#pragma unroll
    for (int lc = 0; lc < LCPC; ++lc)
      a += (double)ws[WS_CS + (size_t)(tid * LCPC + lc) * 96 + e];
    csd[tid] = a * (double)ws[32 + tid];   // t2[c] * colsum_c[e]
  }
  __syncthreads();
  const float* fp = ws + WS_FP;
  double a = 0.0;
#pragma unroll 2
  for (int c = 0; c < 16; ++c) {
    double pc = 0.0;
    for (int lc = 0; lc < LCPC; ++lc) {
      int ch = c * LCPC + lc;
      pc += (double)fp[((size_t)ch * 96 + e) * 320 + tid];
    }
    a += s2d[c] * pc;
  }
  double cst = 0.0;
#pragma unroll
  for (int c = 0; c < 16; ++c) cst += csd[c];
  float x = fmaxf((float)(a + cst) + fcb[e], 0.f);
  if (tid >= N_NODES) x = 0.f;
  double s = (double)x, q = (double)x * (double)x;
  int wv = tid >> 6, ln = tid & 63;
  for (int o = 32; o; o >>= 1) { s += __shfl_down(s, o, 64); q += __shfl_down(q, o, 64); }
  if (ln == 0) { rs[wv] = s; rq[wv] = q; }
  __syncthreads();
  if (tid == 0) {
    double S = 0.0, Q = 0.0;
    for (int w = 0; w < 5; ++w) { S += rs[w]; Q += rq[w]; }
    double m = S / (double)N_NODES;
    double var = Q / (double)N_NODES - m * m;
    mb[0] = (float)m; mb[1] = (float)(1.0 / sqrt(var + 1e-5));
  }
  __syncthreads();
  if (tid < N_NODES)
    ws[WS_NF + (size_t)tid * 96 + e] = g3[e] * (x - mb[0]) * mb[1] + b3[e];
}

// ================= K7: s_proj / r_proj =================
__global__ __launch_bounds__(192) void dgl_k7_proj(const float* __restrict__ fow,
                                                   float* __restrict__ ws) {
  __shared__ float sh[96];
  int nI = blockIdx.x, tid = threadIdx.x;
  if (tid < 96) sh[tid] = ws[WS_NF + (size_t)nI * 96 + tid];
  __syncthreads();
  int col = tid % 96, half = tid / 96;
  float a = 0.f;
#pragma unroll 8
  for (int d = 0; d < 96; ++d) a = fmaf(sh[d], fow[(size_t)(half * 96 + d) * 96 + col], a);
  ws[(half ? WS_RP : WS_SP) + (size_t)nI * 96 + col] = a;
}

// ================= K8: edge relu + logits + gumbel + hard argmax -> adj =================
__global__ __launch_bounds__(256) void dgl_k8_edge(const float* __restrict__ fob,
                                                   const float* __restrict__ fcatw,
                                                   const float* __restrict__ fcatb,
                                                   const float* __restrict__ unif,
                                                   const float* __restrict__ ws,
                                                   float* __restrict__ out) {
  __shared__ float rp[16][100], sp[16][100], bb[96], wa[96], wb[96];
  int tid = threadIdx.x;
  int i0 = blockIdx.y * 16, j0 = blockIdx.x * 16;
  for (int idx = tid; idx < 16 * 96; idx += 256) {
    int r = idx / 96, e = idx % 96;
    int ii = i0 + r, jj = j0 + r;
    rp[r][e] = (ii < N_NODES) ? ws[WS_RP + (size_t)ii * 96 + e] : 0.f;
    sp[r][e] = (jj < N_NODES) ? ws[WS_SP + (size_t)jj * 96 + e] : 0.f;
  }
  if (tid < 96) { bb[tid] = fob[tid]; wa[tid] = fcatw[2 * tid]; wb[tid] = fcatw[2 * tid + 1]; }
  __syncthreads();
  int il = tid >> 4, jl = tid & 15;
  int i = i0 + il, j = j0 + jl;
  float a0 = 0.f, a1 = 0.f;
#pragma unroll 4
  for (int e = 0; e < 96; ++e) {
    float ef = fmaxf(rp[il][e] + sp[jl][e] + bb[e], 0.f);
    a0 = fmaf(ef, wa[e], a0);
    a1 = fmaf(ef, wb[e], a1);
  }
  if (i < N_NODES && j < N_NODES) {
    size_t ue = ((size_t)i * N_NODES + j) * 2;
    float g0 = -logf(-logf(unif[ue] + 1e-20f) + 1e-20f);
    float g1 = -logf(-logf(unif[ue + 1] + 1e-20f) + 1e-20f);
    float z0 = a0 + fcatb[0] + g0;
    float z1 = a1 + fcatb[1] + g1;
    out[(size_t)i * N_NODES + j] = (i == j) ? 0.f : ((z0 >= z1) ? 1.f : 0.f);
  }
}

extern "C" void kernel_launch(void* const* d_in, const int* in_sizes, int n_in,
                              void* d_out, int out_size, void* d_ws, size_t ws_size,
                              hipStream_t stream) {
  const float* nfeat = (const float*)d_in[1];
  const float* w1    = (const float*)d_in[2];
  const float* b1    = (const float*)d_in[3];
  const float* w2    = (const float*)d_in[4];
  const float* b2    = (const float*)d_in[5];
  const float* g1    = (const float*)d_in[6];
  const float* bb1   = (const float*)d_in[7];
  const float* g2    = (const float*)d_in[8];
  const float* bb2   = (const float*)d_in[9];
  const float* g3    = (const float*)d_in[10];
  const float* bb3   = (const float*)d_in[11];
  const float* fcw   = (const float*)d_in[12];
  const float* fcb   = (const float*)d_in[13];
  const float* fow   = (const float*)d_in[14];
  const float* fob   = (const float*)d_in[15];
  const float* fcatw = (const float*)d_in[16];
  const float* fcatb = (const float*)d_in[17];
  const float* unif  = (const float*)d_in[18];
  float* ws  = (float*)d_ws;
  float* out = (float*)d_out;

  dgl_k4b_colsum<<<dim3(K5CH), dim3(384), 0, stream>>>(fcw, ws);
  dgl_k1_conv1_stats<<<dim3(375), dim3(320), 0, stream>>>(nfeat, w1, b1, ws);
  dgl_k2_fin1<<<dim3(1), dim3(64), 0, stream>>>(g1, bb1, ws);
  dgl_k3_conv2<<<dim3(748, 5), dim3(256), 0, stream>>>(nfeat, w1, b1, w2, b2, ws);
  dgl_k4_fin2<<<dim3(1), dim3(512), 0, stream>>>(g2, bb2, ws);
  dgl_k5_fc<<<dim3(K5CH, 10), dim3(192), 0, stream>>>(fcw, ws);
  dgl_k6_bn3<<<dim3(96), dim3(320), 0, stream>>>(fcb, g3, bb3, ws);
  dgl_k7_proj<<<dim3(307), dim3(192), 0, stream>>>(fow, ws);
  dgl_k8_edge<<<dim3(20, 20), dim3(256), 0, stream>>>(fob, fcatw, fcatb, unif, ws, out);
}

// Round 6
// 333.031 us; speedup vs baseline: 1.4486x; 1.0316x over previous
//
#include <hip/hip_runtime.h>

#define N_NODES 307
#define T_LEN   6000
#define L1      5991
#define L2      5982
#define ED      96
#define FDIM    95712
#define NCH2    16
#define LCPC    12                  // l-chunks per channel
#define CHL     499                 // rows per l-chunk (last = 493)
#define K5CH    (NCH2 * LCPC)       // 192 K-chunks, channel-pure

// ---- workspace layout (float offsets) ----
// consts: [0..7]=s1 [8..15]=t1 [16..31]=s2 [32..47]=t2
static const size_t WS_P1 = 256;                    // conv1 stat partials: 375*16
static const size_t WS_P2 = 8192;                   // conv2 stat partials: 3740*32
static const size_t WS_CS = 131072;                 // colsum partials: 192*96
static const size_t WS_NF = 155648;                 // node_feat 307*96
static const size_t WS_SP = 188416;                 // s_proj
static const size_t WS_RP = 221184;                 // r_proj
static const size_t WS_A2 = 262144;                 // a2: 95712*320
static const size_t WS_FP = 262144 + 30627840ull;   // fc partials: 192*96*320
// total = 36,788,224 floats ~= 147.2 MB

// ================= K1: conv1 + relu, channel stats only =================
__global__ __launch_bounds__(320) void dgl_k1_conv1_stats(
    const float* __restrict__ nfeat, const float* __restrict__ w1,
    const float* __restrict__ b1, float* __restrict__ ws) {
  __shared__ float sw1[80], sb1[8];
  __shared__ float sred[5][16];
  int tid = threadIdx.x;
  if (tid < 80) sw1[tid] = w1[tid];
  if (tid < 8)  sb1[tid] = b1[tid];
  __syncthreads();
  int l0 = blockIdx.x * 16;
  int n = tid;
  bool nv = n < N_NODES;
  float xx[26];
#pragma unroll
  for (int j = 0; j < 26; ++j) {
    int t = l0 + j;
    xx[j] = (nv && t < T_LEN) ? nfeat[(size_t)t * N_NODES + n] : 0.f;
  }
  float s[8], q[8];
#pragma unroll
  for (int c = 0; c < 8; ++c) { s[c] = 0.f; q[c] = 0.f; }
#pragma unroll
  for (int dl = 0; dl < 16; ++dl) {
    int l = l0 + dl;
    if (nv && l < L1) {
#pragma unroll
      for (int c = 0; c < 8; ++c) {
        float r = sb1[c];
#pragma unroll
        for (int k = 0; k < 10; ++k) r = fmaf(xx[dl + k], sw1[c * 10 + k], r);
        float z = fmaxf(r, 0.f);
        s[c] += z; q[c] += z * z;
      }
    }
  }
  int wv = tid >> 6, ln = tid & 63;
#pragma unroll
  for (int c = 0; c < 8; ++c) {
    float vs = s[c], vq = q[c];
    for (int o = 32; o; o >>= 1) { vs += __shfl_down(vs, o, 64); vq += __shfl_down(vq, o, 64); }
    if (ln == 0) { sred[wv][c] = vs; sred[wv][8 + c] = vq; }
  }
  __syncthreads();
  if (tid < 16) {
    float t = 0.f;
    for (int w = 0; w < 5; ++w) t += sred[w][tid];
    ws[WS_P1 + (size_t)blockIdx.x * 16 + tid] = t;
  }
}

// ================= K2: finalize bn1 =================
__global__ void dgl_k2_fin1(const float* __restrict__ g1, const float* __restrict__ b1,
                            float* __restrict__ ws) {
  __shared__ double sd[16];
  int tid = threadIdx.x;
  if (tid < 16) {
    double a = 0.0;
    for (int j = 0; j < 375; ++j) a += (double)ws[WS_P1 + (size_t)j * 16 + tid];
    sd[tid] = a;
  }
  __syncthreads();
  if (tid < 8) {
    double cnt = (double)N_NODES * (double)L1;
    double m = sd[tid] / cnt;
    double v = sd[tid + 8] / cnt - m * m;
    double inv = 1.0 / sqrt(v + 1e-5);
    ws[tid]     = (float)((double)g1[tid] * inv);
    ws[8 + tid] = (float)((double)b1[tid] - (double)g1[tid] * inv * m);
  }
}

// ================= K3: fused conv1+bn1 (LDS window) -> conv2 (2 passes) + relu -> a2 + stats =================
__global__ __launch_bounds__(256, 4) void dgl_k3_conv2(
    const float* __restrict__ nfeat, const float* __restrict__ w1, const float* __restrict__ b1,
    const float* __restrict__ w2, const float* __restrict__ b2, float* __restrict__ ws) {
  __shared__ float sx[26][64];
  __shared__ float sz[4][17][64];
  __shared__ float sw2[1280], sw1[80], sb1[8], sb2[16], ss1[8], st1[8];
  __shared__ float wpart[4][8];
  int tid = threadIdx.x;
  int lane = tid & 63, g = tid >> 6;
  int l0 = blockIdx.x * 8, n0 = blockIdx.y * 64;
  for (int i = tid; i < 1280; i += 256) sw2[i] = w2[i];
  if (tid < 80) sw1[tid] = w1[tid];
  if (tid < 8)  { sb1[tid] = b1[tid]; ss1[tid] = ws[tid]; st1[tid] = ws[8 + tid]; }
  if (tid < 16) sb2[tid] = b2[tid];
  for (int i = tid; i < 26 * 64; i += 256) {
    int j = i >> 6, l2 = i & 63;
    int t = l0 + j, nn = n0 + l2;
    sx[j][l2] = (t < T_LEN && nn < N_NODES) ? nfeat[(size_t)t * N_NODES + nn] : 0.f;
  }
  float acc[4][8];
#pragma unroll
  for (int qq = 0; qq < 4; ++qq)
#pragma unroll
    for (int dl = 0; dl < 8; ++dl) acc[qq][dl] = 0.f;
  __syncthreads();
#pragma unroll 1
  for (int p = 0; p < 2; ++p) {
    // group g builds z1 for channel p*4+g into sz[g]
    {
      int c = p * 4 + g;
#pragma unroll
      for (int lz = 0; lz < 17; ++lz) {
        float r = sb1[c];
#pragma unroll
        for (int k = 0; k < 10; ++k) r = fmaf(sx[lz + k][lane], sw1[c * 10 + k], r);
        sz[g][lz][lane] = fmaf(ss1[c], fmaxf(r, 0.f), st1[c]);
      }
    }
    __syncthreads();
#pragma unroll
    for (int c4 = 0; c4 < 4; ++c4) {
      int cin = p * 4 + c4;
      float zr[17];
#pragma unroll
      for (int t = 0; t < 17; ++t) zr[t] = sz[c4][t][lane];
#pragma unroll
      for (int k = 0; k < 10; ++k) {
#pragma unroll
        for (int qq = 0; qq < 4; ++qq) {
          float w = sw2[(g * 4 + qq) * 80 + cin * 10 + k];
#pragma unroll
          for (int dl = 0; dl < 8; ++dl) acc[qq][dl] = fmaf(zr[dl + k], w, acc[qq][dl]);
        }
      }
    }
    __syncthreads();
  }
  int n = n0 + lane;
  bool nv = n < N_NODES;
  float s4[4] = {0.f, 0.f, 0.f, 0.f}, q4[4] = {0.f, 0.f, 0.f, 0.f};
#pragma unroll
  for (int qq = 0; qq < 4; ++qq) {
    int c2 = g * 4 + qq;
#pragma unroll
    for (int dl = 0; dl < 8; ++dl) {
      int l = l0 + dl;
      float v = 0.f;
      if (nv && l < L2) v = fmaxf(acc[qq][dl] + sb2[c2], 0.f);
      if (l < L2) ws[WS_A2 + ((size_t)c2 * L2 + l) * 320 + n] = v;
      s4[qq] += v; q4[qq] += v * v;
    }
  }
#pragma unroll
  for (int qq = 0; qq < 4; ++qq) {
    float vs = s4[qq], vq = q4[qq];
    for (int o = 32; o; o >>= 1) { vs += __shfl_down(vs, o, 64); vq += __shfl_down(vq, o, 64); }
    if (lane == 0) { wpart[g][qq] = vs; wpart[g][4 + qq] = vq; }
  }
  __syncthreads();
  if (tid < 32) {
    int c2 = tid & 15; bool isq = tid >= 16;
    float v = wpart[c2 >> 2][(isq ? 4 : 0) + (c2 & 3)];
    ws[WS_P2 + ((size_t)blockIdx.y * gridDim.x + blockIdx.x) * 32 + tid] = v;
  }
}

// ================= K4: finalize bn2 =================
__global__ __launch_bounds__(512) void dgl_k4_fin2(const float* __restrict__ g2,
                                                   const float* __restrict__ b2,
                                                   float* __restrict__ ws) {
  __shared__ double dd[32][17];
  int tid = threadIdx.x;
  int v = tid >> 4, p = tid & 15;
  double a = 0.0;
  for (int j = p; j < 3740; j += 16) a += (double)ws[WS_P2 + (size_t)j * 32 + v];
  dd[v][p] = a;
  __syncthreads();
  if (tid < 32) {
    double s = 0.0;
    for (int pp = 0; pp < 16; ++pp) s += dd[tid][pp];
    dd[tid][16] = s;
  }
  __syncthreads();
  if (tid < 16) {
    double cnt = (double)N_NODES * (double)L2;
    double m = dd[tid][16] / cnt;
    double var = dd[tid + 16][16] / cnt - m * m;
    double inv = 1.0 / sqrt(var + 1e-5);
    ws[16 + tid] = (float)((double)g2[tid] * inv);
    ws[32 + tid] = (float)((double)b2[tid] - (double)g2[tid] * inv * m);
  }
}

// ================= K4b: per-channel-chunk column sums of fc_w =================
__global__ __launch_bounds__(384) void dgl_k4b_colsum(const float* __restrict__ fcw,
                                                      float* __restrict__ ws) {
  __shared__ float red[4][96];
  int b = blockIdx.x;                 // 0..191
  int c = b / LCPC, lc = b % LCPC;
  int clen = (lc == LCPC - 1) ? (L2 - CHL * (LCPC - 1)) : CHL;
  size_t fb = (size_t)c * L2 + (size_t)lc * CHL;
  int tid = threadIdx.x, rg = tid / 96, e = tid % 96;
  float a = 0.f;
  for (int r = rg; r < clen; r += 4) a += fcw[(fb + r) * 96 + e];
  red[rg][e] = a;
  __syncthreads();
  if (tid < 96) {
    float t = red[0][tid] + red[1][tid] + red[2][tid] + red[3][tid];
    ws[WS_CS + (size_t)b * 96 + tid] = t;
  }
}

// ================= K5: split-K GEMM, 64n x 96e block tile, 8n x 4e thread tile =================
__global__ __launch_bounds__(192) void dgl_k5_fc(const float* __restrict__ fcw,
                                                 float* __restrict__ ws) {
  __shared__ float As[16][68];
  __shared__ float Bs[16][100];
  int tid = threadIdx.x;
  int ch = blockIdx.x;                // 0..191
  int c = ch / LCPC, lc = ch % LCPC;
  int clen = (lc == LCPC - 1) ? (L2 - CHL * (LCPC - 1)) : CHL;
  size_t fb = (size_t)c * L2 + (size_t)lc * CHL;
  int n0 = blockIdx.y * 64;
  const float* a2 = ws + WS_A2;
  int tn = tid / 24, te = tid % 24;   // thread tile 8n x 4e
  float acc[8][4];
#pragma unroll
  for (int i = 0; i < 8; ++i)
#pragma unroll
    for (int j = 0; j < 4; ++j) acc[i][j] = 0.f;
  const float4 z4 = make_float4(0.f, 0.f, 0.f, 0.f);

  for (int ks = 0; ks < 32; ++ks) {
    int r0 = ks * 16;
    // stage A: 16 rows x 64 cols = 256 float4 slots
    for (int i = tid; i < 256; i += 192) {
      int r = i >> 4, c4 = i & 15;
      int rr = r0 + r;
      float4 v = (rr < clen) ? *(const float4*)(a2 + (fb + rr) * 320 + n0 + c4 * 4) : z4;
      *(float4*)(&As[r][c4 * 4]) = v;
    }
    // stage B: 16 rows x 96 cols = 384 float4 slots
    for (int i = tid; i < 384; i += 192) {
      int r = i / 24, c4 = i % 24;
      int rr = r0 + r;
      float4 v = (rr < clen) ? *(const float4*)(fcw + (fb + rr) * 96 + c4 * 4) : z4;
      *(float4*)(&Bs[r][c4 * 4]) = v;
    }
    __syncthreads();
#pragma unroll
    for (int kk = 0; kk < 16; ++kk) {
      float a[8], b[4];
      *(float4*)(a)     = *(float4*)(&As[kk][tn * 8]);
      *(float4*)(a + 4) = *(float4*)(&As[kk][tn * 8 + 4]);
      *(float4*)(b)     = *(float4*)(&Bs[kk][te * 4]);
#pragma unroll
      for (int i = 0; i < 8; ++i)
#pragma unroll
        for (int j = 0; j < 4; ++j) acc[i][j] = fmaf(a[i], b[j], acc[i][j]);
    }
    __syncthreads();
  }
  float* fp = ws + WS_FP;
#pragma unroll
  for (int j = 0; j < 4; ++j) {
    int e = te * 4 + j;
    size_t base = ((size_t)ch * 96 + e) * 320 + n0 + tn * 8;
    float4 o1 = {acc[0][j], acc[1][j], acc[2][j], acc[3][j]};
    float4 o2 = {acc[4][j], acc[5][j], acc[6][j], acc[7][j]};
    *(float4*)(fp + base) = o1;
    *(float4*)(fp + base + 4) = o2;
  }
}

// ================= K6: fp64 combine (s2*P + t2*colsum + fcb) + relu + bn3 =================
__global__ __launch_bounds__(320) void dgl_k6_bn3(const float* __restrict__ fcb,
                                                  const float* __restrict__ g3,
                                                  const float* __restrict__ b3,
                                                  float* __restrict__ ws) {
  int e = blockIdx.x, tid = threadIdx.x;
  __shared__ double s2d[16], csd[16];
  __shared__ double rs[5], rq[5];
  __shared__ float mb[2];
  if (tid < 16) {
    s2d[tid] = (double)ws[16 + tid];
    double a = 0.0;
#pragma unroll
    for (int lc = 0; lc < LCPC; ++lc)
      a += (double)ws[WS_CS + (size_t)(tid * LCPC + lc) * 96 + e];
    csd[tid] = a * (double)ws[32 + tid];   // t2[c] * colsum_c[e]
  }
  __syncthreads();
  const float* fp = ws + WS_FP;
  double a = 0.0;
#pragma unroll 2
  for (int c = 0; c < 16; ++c) {
    double pc = 0.0;
    for (int lc = 0; lc < LCPC; ++lc) {
      int ch = c * LCPC + lc;
      pc += (double)fp[((size_t)ch * 96 + e) * 320 + tid];
    }
    a += s2d[c] * pc;
  }
  double cst = 0.0;
#pragma unroll
  for (int c = 0; c < 16; ++c) cst += csd[c];
  float x = fmaxf((float)(a + cst) + fcb[e], 0.f);
  if (tid >= N_NODES) x = 0.f;
  double s = (double)x, q = (double)x * (double)x;
  int wv = tid >> 6, ln = tid & 63;
  for (int o = 32; o; o >>= 1) { s += __shfl_down(s, o, 64); q += __shfl_down(q, o, 64); }
  if (ln == 0) { rs[wv] = s; rq[wv] = q; }
  __syncthreads();
  if (tid == 0) {
    double S = 0.0, Q = 0.0;
    for (int w = 0; w < 5; ++w) { S += rs[w]; Q += rq[w]; }
    double m = S / (double)N_NODES;
    double var = Q / (double)N_NODES - m * m;
    mb[0] = (float)m; mb[1] = (float)(1.0 / sqrt(var + 1e-5));
  }
  __syncthreads();
  if (tid < N_NODES)
    ws[WS_NF + (size_t)tid * 96 + e] = g3[e] * (x - mb[0]) * mb[1] + b3[e];
}

// ================= K7: s_proj / r_proj =================
__global__ __launch_bounds__(192) void dgl_k7_proj(const float* __restrict__ fow,
                                                   float* __restrict__ ws) {
  __shared__ float sh[96];
  int nI = blockIdx.x, tid = threadIdx.x;
  if (tid < 96) sh[tid] = ws[WS_NF + (size_t)nI * 96 + tid];
  __syncthreads();
  int col = tid % 96, half = tid / 96;
  float a = 0.f;
#pragma unroll 8
  for (int d = 0; d < 96; ++d) a = fmaf(sh[d], fow[(size_t)(half * 96 + d) * 96 + col], a);
  ws[(half ? WS_RP : WS_SP) + (size_t)nI * 96 + col] = a;
}

// ================= K8: edge relu + logits + gumbel + hard argmax -> adj =================
__global__ __launch_bounds__(256) void dgl_k8_edge(const float* __restrict__ fob,
                                                   const float* __restrict__ fcatw,
                                                   const float* __restrict__ fcatb,
                                                   const float* __restrict__ unif,
                                                   const float* __restrict__ ws,
                                                   float* __restrict__ out) {
  __shared__ float rp[16][100], sp[16][100], bb[96], wa[96], wb[96];
  int tid = threadIdx.x;
  int i0 = blockIdx.y * 16, j0 = blockIdx.x * 16;
  for (int idx = tid; idx < 16 * 96; idx += 256) {
    int r = idx / 96, e = idx % 96;
    int ii = i0 + r, jj = j0 + r;
    rp[r][e] = (ii < N_NODES) ? ws[WS_RP + (size_t)ii * 96 + e] : 0.f;
    sp[r][e] = (jj < N_NODES) ? ws[WS_SP + (size_t)jj * 96 + e] : 0.f;
  }
  if (tid < 96) { bb[tid] = fob[tid]; wa[tid] = fcatw[2 * tid]; wb[tid] = fcatw[2 * tid + 1]; }
  __syncthreads();
  int il = tid >> 4, jl = tid & 15;
  int i = i0 + il, j = j0 + jl;
  float a0 = 0.f, a1 = 0.f;
#pragma unroll 4
  for (int e = 0; e < 96; ++e) {
    float ef = fmaxf(rp[il][e] + sp[jl][e] + bb[e], 0.f);
    a0 = fmaf(ef, wa[e], a0);
    a1 = fmaf(ef, wb[e], a1);
  }
  if (i < N_NODES && j < N_NODES) {
    size_t ue = ((size_t)i * N_NODES + j) * 2;
    float g0 = -logf(-logf(unif[ue] + 1e-20f) + 1e-20f);
    float g1 = -logf(-logf(unif[ue + 1] + 1e-20f) + 1e-20f);
    float z0 = a0 + fcatb[0] + g0;
    float z1 = a1 + fcatb[1] + g1;
    out[(size_t)i * N_NODES + j] = (i == j) ? 0.f : ((z0 >= z1) ? 1.f : 0.f);
  }
}

extern "C" void kernel_launch(void* const* d_in, const int* in_sizes, int n_in,
                              void* d_out, int out_size, void* d_ws, size_t ws_size,
                              hipStream_t stream) {
  const float* nfeat = (const float*)d_in[1];
  const float* w1    = (const float*)d_in[2];
  const float* b1    = (const float*)d_in[3];
  const float* w2    = (const float*)d_in[4];
  const float* b2    = (const float*)d_in[5];
  const float* g1    = (const float*)d_in[6];
  const float* bb1   = (const float*)d_in[7];
  const float* g2    = (const float*)d_in[8];
  const float* bb2   = (const float*)d_in[9];
  const float* g3    = (const float*)d_in[10];
  const float* bb3   = (const float*)d_in[11];
  const float* fcw   = (const float*)d_in[12];
  const float* fcb   = (const float*)d_in[13];
  const float* fow   = (const float*)d_in[14];
  const float* fob   = (const float*)d_in[15];
  const float* fcatw = (const float*)d_in[16];
  const float* fcatb = (const float*)d_in[17];
  const float* unif  = (const float*)d_in[18];
  float* ws  = (float*)d_ws;
  float* out = (float*)d_out;

  dgl_k4b_colsum<<<dim3(K5CH), dim3(384), 0, stream>>>(fcw, ws);
  dgl_k1_conv1_stats<<<dim3(375), dim3(320), 0, stream>>>(nfeat, w1, b1, ws);
  dgl_k2_fin1<<<dim3(1), dim3(64), 0, stream>>>(g1, bb1, ws);
  dgl_k3_conv2<<<dim3(748, 5), dim3(256), 0, stream>>>(nfeat, w1, b1, w2, b2, ws);
  dgl_k4_fin2<<<dim3(1), dim3(512), 0, stream>>>(g2, bb2, ws);
  dgl_k5_fc<<<dim3(K5CH, 5), dim3(192), 0, stream>>>(fcw, ws);
  dgl_k6_bn3<<<dim3(96), dim3(320), 0, stream>>>(fcb, g3, bb3, ws);
  dgl_k7_proj<<<dim3(307), dim3(192), 0, stream>>>(fow, ws);
  dgl_k8_edge<<<dim3(20, 20), dim3(256), 0, stream>>>(fob, fcatw, fcatb, unif, ws, out);
}

// Round 7
// 329.361 us; speedup vs baseline: 1.4647x; 1.0111x over previous
//
#include <hip/hip_runtime.h>

#define N_NODES 307
#define T_LEN   6000
#define L1      5991
#define L2      5982
#define ED      96
#define FDIM    95712
#define NCH2    16
#define LCPC    12                  // l-chunks per channel
#define CHL     499                 // rows per l-chunk (last = 493)
#define K5CH    (NCH2 * LCPC)       // 192 K-chunks, channel-pure

// ---- workspace layout (float offsets) ----
// consts: [0..7]=s1 [8..15]=t1 [16..31]=s2 [32..47]=t2
static const size_t WS_P1 = 256;                    // conv1 stat partials: 375*16
static const size_t WS_P2 = 8192;                   // conv2 stat partials: 3740*32
static const size_t WS_CS = 131072;                 // colsum partials: 192*96
static const size_t WS_NF = 155648;                 // node_feat 307*96
static const size_t WS_SP = 188416;                 // s_proj
static const size_t WS_RP = 221184;                 // r_proj
static const size_t WS_A2 = 262144;                 // a2: 95712*320
static const size_t WS_FP = 262144 + 30627840ull;   // fc partials: 192*96*320
// total = 36,788,224 floats ~= 147.2 MB

// async 16B global->LDS (wave-uniform LDS base + lane*16)
__device__ __forceinline__ void gl_lds16(const float* g, float* l) {
  __builtin_amdgcn_global_load_lds((const __attribute__((address_space(1))) void*)g,
                                   (__attribute__((address_space(3))) void*)l, 16, 0, 0);
}

// ================= K1: conv1 + relu, channel stats only =================
__global__ __launch_bounds__(320) void dgl_k1_conv1_stats(
    const float* __restrict__ nfeat, const float* __restrict__ w1,
    const float* __restrict__ b1, float* __restrict__ ws) {
  __shared__ float sw1[80], sb1[8];
  __shared__ float sred[5][16];
  int tid = threadIdx.x;
  if (tid < 80) sw1[tid] = w1[tid];
  if (tid < 8)  sb1[tid] = b1[tid];
  __syncthreads();
  int l0 = blockIdx.x * 16;
  int n = tid;
  bool nv = n < N_NODES;
  float xx[26];
#pragma unroll
  for (int j = 0; j < 26; ++j) {
    int t = l0 + j;
    xx[j] = (nv && t < T_LEN) ? nfeat[(size_t)t * N_NODES + n] : 0.f;
  }
  float s[8], q[8];
#pragma unroll
  for (int c = 0; c < 8; ++c) { s[c] = 0.f; q[c] = 0.f; }
#pragma unroll
  for (int dl = 0; dl < 16; ++dl) {
    int l = l0 + dl;
    if (nv && l < L1) {
#pragma unroll
      for (int c = 0; c < 8; ++c) {
        float r = sb1[c];
#pragma unroll
        for (int k = 0; k < 10; ++k) r = fmaf(xx[dl + k], sw1[c * 10 + k], r);
        float z = fmaxf(r, 0.f);
        s[c] += z; q[c] += z * z;
      }
    }
  }
  int wv = tid >> 6, ln = tid & 63;
#pragma unroll
  for (int c = 0; c < 8; ++c) {
    float vs = s[c], vq = q[c];
    for (int o = 32; o; o >>= 1) { vs += __shfl_down(vs, o, 64); vq += __shfl_down(vq, o, 64); }
    if (ln == 0) { sred[wv][c] = vs; sred[wv][8 + c] = vq; }
  }
  __syncthreads();
  if (tid < 16) {
    float t = 0.f;
    for (int w = 0; w < 5; ++w) t += sred[w][tid];
    ws[WS_P1 + (size_t)blockIdx.x * 16 + tid] = t;
  }
}

// ================= K2: finalize bn1 =================
__global__ void dgl_k2_fin1(const float* __restrict__ g1, const float* __restrict__ b1,
                            float* __restrict__ ws) {
  __shared__ double sd[16];
  int tid = threadIdx.x;
  if (tid < 16) {
    double a = 0.0;
    for (int j = 0; j < 375; ++j) a += (double)ws[WS_P1 + (size_t)j * 16 + tid];
    sd[tid] = a;
  }
  __syncthreads();
  if (tid < 8) {
    double cnt = (double)N_NODES * (double)L1;
    double m = sd[tid] / cnt;
    double v = sd[tid + 8] / cnt - m * m;
    double inv = 1.0 / sqrt(v + 1e-5);
    ws[tid]     = (float)((double)g1[tid] * inv);
    ws[8 + tid] = (float)((double)b1[tid] - (double)g1[tid] * inv * m);
  }
}

// ================= K3: fused conv1+bn1 (LDS window) -> conv2 (2 passes) + relu -> a2 + stats =================
__global__ __launch_bounds__(256, 4) void dgl_k3_conv2(
    const float* __restrict__ nfeat, const float* __restrict__ w1, const float* __restrict__ b1,
    const float* __restrict__ w2, const float* __restrict__ b2, float* __restrict__ ws) {
  __shared__ float sx[26][64];
  __shared__ float sz[4][17][64];
  __shared__ float sw2[1280], sw1[80], sb1[8], sb2[16], ss1[8], st1[8];
  __shared__ float wpart[4][8];
  int tid = threadIdx.x;
  int lane = tid & 63, g = tid >> 6;
  int l0 = blockIdx.x * 8, n0 = blockIdx.y * 64;
  for (int i = tid; i < 1280; i += 256) sw2[i] = w2[i];
  if (tid < 80) sw1[tid] = w1[tid];
  if (tid < 8)  { sb1[tid] = b1[tid]; ss1[tid] = ws[tid]; st1[tid] = ws[8 + tid]; }
  if (tid < 16) sb2[tid] = b2[tid];
  for (int i = tid; i < 26 * 64; i += 256) {
    int j = i >> 6, l2 = i & 63;
    int t = l0 + j, nn = n0 + l2;
    sx[j][l2] = (t < T_LEN && nn < N_NODES) ? nfeat[(size_t)t * N_NODES + nn] : 0.f;
  }
  float acc[4][8];
#pragma unroll
  for (int qq = 0; qq < 4; ++qq)
#pragma unroll
    for (int dl = 0; dl < 8; ++dl) acc[qq][dl] = 0.f;
  __syncthreads();
#pragma unroll 1
  for (int p = 0; p < 2; ++p) {
    // group g builds z1 for channel p*4+g into sz[g]
    {
      int c = p * 4 + g;
#pragma unroll
      for (int lz = 0; lz < 17; ++lz) {
        float r = sb1[c];
#pragma unroll
        for (int k = 0; k < 10; ++k) r = fmaf(sx[lz + k][lane], sw1[c * 10 + k], r);
        sz[g][lz][lane] = fmaf(ss1[c], fmaxf(r, 0.f), st1[c]);
      }
    }
    __syncthreads();
#pragma unroll
    for (int c4 = 0; c4 < 4; ++c4) {
      int cin = p * 4 + c4;
      float zr[17];
#pragma unroll
      for (int t = 0; t < 17; ++t) zr[t] = sz[c4][t][lane];
#pragma unroll
      for (int k = 0; k < 10; ++k) {
#pragma unroll
        for (int qq = 0; qq < 4; ++qq) {
          float w = sw2[(g * 4 + qq) * 80 + cin * 10 + k];
#pragma unroll
          for (int dl = 0; dl < 8; ++dl) acc[qq][dl] = fmaf(zr[dl + k], w, acc[qq][dl]);
        }
      }
    }
    __syncthreads();
  }
  int n = n0 + lane;
  bool nv = n < N_NODES;
  float s4[4] = {0.f, 0.f, 0.f, 0.f}, q4[4] = {0.f, 0.f, 0.f, 0.f};
#pragma unroll
  for (int qq = 0; qq < 4; ++qq) {
    int c2 = g * 4 + qq;
#pragma unroll
    for (int dl = 0; dl < 8; ++dl) {
      int l = l0 + dl;
      float v = 0.f;
      if (nv && l < L2) v = fmaxf(acc[qq][dl] + sb2[c2], 0.f);
      if (l < L2) ws[WS_A2 + ((size_t)c2 * L2 + l) * 320 + n] = v;
      s4[qq] += v; q4[qq] += v * v;
    }
  }
#pragma unroll
  for (int qq = 0; qq < 4; ++qq) {
    float vs = s4[qq], vq = q4[qq];
    for (int o = 32; o; o >>= 1) { vs += __shfl_down(vs, o, 64); vq += __shfl_down(vq, o, 64); }
    if (lane == 0) { wpart[g][qq] = vs; wpart[g][4 + qq] = vq; }
  }
  __syncthreads();
  if (tid < 32) {
    int c2 = tid & 15; bool isq = tid >= 16;
    float v = wpart[c2 >> 2][(isq ? 4 : 0) + (c2 & 3)];
    ws[WS_P2 + ((size_t)blockIdx.y * gridDim.x + blockIdx.x) * 32 + tid] = v;
  }
}

// ================= K4: finalize bn2 =================
__global__ __launch_bounds__(512) void dgl_k4_fin2(const float* __restrict__ g2,
                                                   const float* __restrict__ b2,
                                                   float* __restrict__ ws) {
  __shared__ double dd[32][17];
  int tid = threadIdx.x;
  int v = tid >> 4, p = tid & 15;
  double a = 0.0;
  for (int j = p; j < 3740; j += 16) a += (double)ws[WS_P2 + (size_t)j * 32 + v];
  dd[v][p] = a;
  __syncthreads();
  if (tid < 32) {
    double s = 0.0;
    for (int pp = 0; pp < 16; ++pp) s += dd[tid][pp];
    dd[tid][16] = s;
  }
  __syncthreads();
  if (tid < 16) {
    double cnt = (double)N_NODES * (double)L2;
    double m = dd[tid][16] / cnt;
    double var = dd[tid + 16][16] / cnt - m * m;
    double inv = 1.0 / sqrt(var + 1e-5);
    ws[16 + tid] = (float)((double)g2[tid] * inv);
    ws[32 + tid] = (float)((double)b2[tid] - (double)g2[tid] * inv * m);
  }
}

// ================= K4b: per-channel-chunk column sums of fc_w =================
__global__ __launch_bounds__(384) void dgl_k4b_colsum(const float* __restrict__ fcw,
                                                      float* __restrict__ ws) {
  __shared__ float red[4][96];
  int b = blockIdx.x;                 // 0..191
  int c = b / LCPC, lc = b % LCPC;
  int clen = (lc == LCPC - 1) ? (L2 - CHL * (LCPC - 1)) : CHL;
  size_t fb = (size_t)c * L2 + (size_t)lc * CHL;
  int tid = threadIdx.x, rg = tid / 96, e = tid % 96;
  float a = 0.f;
  for (int r = rg; r < clen; r += 4) a += fcw[(fb + r) * 96 + e];
  red[rg][e] = a;
  __syncthreads();
  if (tid < 96) {
    float t = red[0][tid] + red[1][tid] + red[2][tid] + red[3][tid];
    ws[WS_CS + (size_t)b * 96 + tid] = t;
  }
}

// ================= K5: split-K GEMM, async 2-phase double-buffer =================
// A: global_load_lds (unguarded tail reads stay inside ws; nullified by B=0)
// B: reg-staged with clen guard (zeros for pad rows)
__global__ __launch_bounds__(192) void dgl_k5_fc(const float* __restrict__ fcw,
                                                 float* __restrict__ ws) {
  __shared__ float As[2][16][64];
  __shared__ float Bs[2][16][100];
  int tid = threadIdx.x;
  int ch = blockIdx.x;                // 0..191
  int c = ch / LCPC, lc = ch % LCPC;
  int clen = (lc == LCPC - 1) ? (L2 - CHL * (LCPC - 1)) : CHL;
  size_t fb = (size_t)c * L2 + (size_t)lc * CHL;
  int n0 = blockIdx.y * 64;
  const float* a2 = ws + WS_A2;
  int tn = tid / 24, te = tid % 24;   // thread tile 8n x 4e
  int wid = tid >> 6, lane = tid & 63;
  int arow = lane >> 4, acol = (lane & 15) * 4;   // per-lane src within A instr
  int b0r = tid / 24, b0c = (tid % 24) * 4;              // B slot 0 (rows 0..7)
  int b1r = (tid + 192) / 24, b1c = ((tid + 192) % 24) * 4; // B slot 1 (rows 8..15)
  const float4 z4 = make_float4(0.f, 0.f, 0.f, 0.f);
  float4 vb0 = z4, vb1 = z4;
  float acc[8][4];
#pragma unroll
  for (int i = 0; i < 8; ++i)
#pragma unroll
    for (int j = 0; j < 4; ++j) acc[i][j] = 0.f;

#define K5_STAGE_A(BUF, KS) do {                                                \
    if (wid < 2) {                                                              \
      int rb_ = wid * 8;                                                        \
      const float* g0_ = a2 + (fb + (size_t)((KS) * 16 + rb_ + arow)) * 320     \
                            + n0 + acol;                                        \
      gl_lds16(g0_, &As[BUF][rb_][0]);                                          \
      const float* g1_ = g0_ + 4 * 320;                                         \
      gl_lds16(g1_, &As[BUF][rb_ + 4][0]);                                      \
    }                                                                           \
  } while (0)

#define K5_LOAD_B(KS) do {                                                      \
    int r0_ = (KS) * 16;                                                        \
    int ra_ = r0_ + b0r, rb2_ = r0_ + b1r;                                      \
    vb0 = (ra_ < clen) ? *(const float4*)(fcw + (fb + ra_) * 96 + b0c) : z4;    \
    vb1 = (rb2_ < clen) ? *(const float4*)(fcw + (fb + rb2_) * 96 + b1c) : z4;  \
  } while (0)

#define K5_WRITE_B(BUF) do {                                                    \
    *(float4*)(&Bs[BUF][b0r][b0c]) = vb0;                                       \
    *(float4*)(&Bs[BUF][b1r][b1c]) = vb1;                                       \
  } while (0)

  K5_STAGE_A(0, 0);
  K5_LOAD_B(0);
  K5_WRITE_B(0);
  __syncthreads();   // drains vmcnt (A async loads) + lgkm (B writes)
  int cur = 0;
  for (int ks = 0; ks < 32; ++ks) {
    if (ks < 31) { K5_STAGE_A(cur ^ 1, ks + 1); K5_LOAD_B(ks + 1); }
#pragma unroll
    for (int kk = 0; kk < 16; ++kk) {
      float a[8], b[4];
      *(float4*)(a)     = *(float4*)(&As[cur][kk][tn * 8]);
      *(float4*)(a + 4) = *(float4*)(&As[cur][kk][tn * 8 + 4]);
      *(float4*)(b)     = *(float4*)(&Bs[cur][kk][te * 4]);
#pragma unroll
      for (int i = 0; i < 8; ++i)
#pragma unroll
        for (int j = 0; j < 4; ++j) acc[i][j] = fmaf(a[i], b[j], acc[i][j]);
    }
    if (ks < 31) {
      K5_WRITE_B(cur ^ 1);
      __syncthreads();   // next-buffer A (vmcnt) + B (lgkm) complete for all
      cur ^= 1;
    }
  }
  float* fp = ws + WS_FP;
#pragma unroll
  for (int j = 0; j < 4; ++j) {
    int e = te * 4 + j;
    size_t base = ((size_t)ch * 96 + e) * 320 + n0 + tn * 8;
    float4 o1 = {acc[0][j], acc[1][j], acc[2][j], acc[3][j]};
    float4 o2 = {acc[4][j], acc[5][j], acc[6][j], acc[7][j]};
    *(float4*)(fp + base) = o1;
    *(float4*)(fp + base + 4) = o2;
  }
#undef K5_STAGE_A
#undef K5_LOAD_B
#undef K5_WRITE_B
}

// ================= K6: fp64 combine (s2*P + t2*colsum + fcb) + relu + bn3 =================
__global__ __launch_bounds__(320) void dgl_k6_bn3(const float* __restrict__ fcb,
                                                  const float* __restrict__ g3,
                                                  const float* __restrict__ b3,
                                                  float* __restrict__ ws) {
  int e = blockIdx.x, tid = threadIdx.x;
  __shared__ double s2d[16], csd[16];
  __shared__ double rs[5], rq[5];
  __shared__ float mb[2];
  if (tid < 16) {
    s2d[tid] = (double)ws[16 + tid];
    double a = 0.0;
#pragma unroll
    for (int lc = 0; lc < LCPC; ++lc)
      a += (double)ws[WS_CS + (size_t)(tid * LCPC + lc) * 96 + e];
    csd[tid] = a * (double)ws[32 + tid];   // t2[c] * colsum_c[e]
  }
  __syncthreads();
  const float* fp = ws + WS_FP;
  double a = 0.0;
#pragma unroll 2
  for (int c = 0; c < 16; ++c) {
    double pc = 0.0;
    for (int lc = 0; lc < LCPC; ++lc) {
      int ch = c * LCPC + lc;
      pc += (double)fp[((size_t)ch * 96 + e) * 320 + tid];
    }
    a += s2d[c] * pc;
  }
  double cst = 0.0;
#pragma unroll
  for (int c = 0; c < 16; ++c) cst += csd[c];
  float x = fmaxf((float)(a + cst) + fcb[e], 0.f);
  if (tid >= N_NODES) x = 0.f;
  double s = (double)x, q = (double)x * (double)x;
  int wv = tid >> 6, ln = tid & 63;
  for (int o = 32; o; o >>= 1) { s += __shfl_down(s, o, 64); q += __shfl_down(q, o, 64); }
  if (ln == 0) { rs[wv] = s; rq[wv] = q; }
  __syncthreads();
  if (tid == 0) {
    double S = 0.0, Q = 0.0;
    for (int w = 0; w < 5; ++w) { S += rs[w]; Q += rq[w]; }
    double m = S / (double)N_NODES;
    double var = Q / (double)N_NODES - m * m;
    mb[0] = (float)m; mb[1] = (float)(1.0 / sqrt(var + 1e-5));
  }
  __syncthreads();
  if (tid < N_NODES)
    ws[WS_NF + (size_t)tid * 96 + e] = g3[e] * (x - mb[0]) * mb[1] + b3[e];
}

// ================= K7: s_proj / r_proj =================
__global__ __launch_bounds__(192) void dgl_k7_proj(const float* __restrict__ fow,
                                                   float* __restrict__ ws) {
  __shared__ float sh[96];
  int nI = blockIdx.x, tid = threadIdx.x;
  if (tid < 96) sh[tid] = ws[WS_NF + (size_t)nI * 96 + tid];
  __syncthreads();
  int col = tid % 96, half = tid / 96;
  float a = 0.f;
#pragma unroll 8
  for (int d = 0; d < 96; ++d) a = fmaf(sh[d], fow[(size_t)(half * 96 + d) * 96 + col], a);
  ws[(half ? WS_RP : WS_SP) + (size_t)nI * 96 + col] = a;
}

// ================= K8: edge relu + logits + gumbel + hard argmax -> adj =================
__global__ __launch_bounds__(256) void dgl_k8_edge(const float* __restrict__ fob,
                                                   const float* __restrict__ fcatw,
                                                   const float* __restrict__ fcatb,
                                                   const float* __restrict__ unif,
                                                   const float* __restrict__ ws,
                                                   float* __restrict__ out) {
  __shared__ float rp[16][100], sp[16][100], bb[96], wa[96], wb[96];
  int tid = threadIdx.x;
  int i0 = blockIdx.y * 16, j0 = blockIdx.x * 16;
  for (int idx = tid; idx < 16 * 96; idx += 256) {
    int r = idx / 96, e = idx % 96;
    int ii = i0 + r, jj = j0 + r;
    rp[r][e] = (ii < N_NODES) ? ws[WS_RP + (size_t)ii * 96 + e] : 0.f;
    sp[r][e] = (jj < N_NODES) ? ws[WS_SP + (size_t)jj * 96 + e] : 0.f;
  }
  if (tid < 96) { bb[tid] = fob[tid]; wa[tid] = fcatw[2 * tid]; wb[tid] = fcatw[2 * tid + 1]; }
  __syncthreads();
  int il = tid >> 4, jl = tid & 15;
  int i = i0 + il, j = j0 + jl;
  float a0 = 0.f, a1 = 0.f;
#pragma unroll 4
  for (int e = 0; e < 96; ++e) {
    float ef = fmaxf(rp[il][e] + sp[jl][e] + bb[e], 0.f);
    a0 = fmaf(ef, wa[e], a0);
    a1 = fmaf(ef, wb[e], a1);
  }
  if (i < N_NODES && j < N_NODES) {
    size_t ue = ((size_t)i * N_NODES + j) * 2;
    float g0 = -logf(-logf(unif[ue] + 1e-20f) + 1e-20f);
    float g1 = -logf(-logf(unif[ue + 1] + 1e-20f) + 1e-20f);
    float z0 = a0 + fcatb[0] + g0;
    float z1 = a1 + fcatb[1] + g1;
    out[(size_t)i * N_NODES + j] = (i == j) ? 0.f : ((z0 >= z1) ? 1.f : 0.f);
  }
}

extern "C" void kernel_launch(void* const* d_in, const int* in_sizes, int n_in,
                              void* d_out, int out_size, void* d_ws, size_t ws_size,
                              hipStream_t stream) {
  const float* nfeat = (const float*)d_in[1];
  const float* w1    = (const float*)d_in[2];
  const float* b1    = (const float*)d_in[3];
  const float* w2    = (const float*)d_in[4];
  const float* b2    = (const float*)d_in[5];
  const float* g1    = (const float*)d_in[6];
  const float* bb1   = (const float*)d_in[7];
  const float* g2    = (const float*)d_in[8];
  const float* bb2   = (const float*)d_in[9];
  const float* g3    = (const float*)d_in[10];
  const float* bb3   = (const float*)d_in[11];
  const float* fcw   = (const float*)d_in[12];
  const float* fcb   = (const float*)d_in[13];
  const float* fow   = (const float*)d_in[14];
  const float* fob   = (const float*)d_in[15];
  const float* fcatw = (const float*)d_in[16];
  const float* fcatb = (const float*)d_in[17];
  const float* unif  = (const float*)d_in[18];
  float* ws  = (float*)d_ws;
  float* out = (float*)d_out;

  dgl_k4b_colsum<<<dim3(K5CH), dim3(384), 0, stream>>>(fcw, ws);
  dgl_k1_conv1_stats<<<dim3(375), dim3(320), 0, stream>>>(nfeat, w1, b1, ws);
  dgl_k2_fin1<<<dim3(1), dim3(64), 0, stream>>>(g1, bb1, ws);
  dgl_k3_conv2<<<dim3(748, 5), dim3(256), 0, stream>>>(nfeat, w1, b1, w2, b2, ws);
  dgl_k4_fin2<<<dim3(1), dim3(512), 0, stream>>>(g2, bb2, ws);
  dgl_k5_fc<<<dim3(K5CH, 5), dim3(192), 0, stream>>>(fcw, ws);
  dgl_k6_bn3<<<dim3(96), dim3(320), 0, stream>>>(fcb, g3, bb3, ws);
  dgl_k7_proj<<<dim3(307), dim3(192), 0, stream>>>(fow, ws);
  dgl_k8_edge<<<dim3(20, 20), dim3(256), 0, stream>>>(fob, fcatw, fcatb, unif, ws, out);
}